// Round 1
// baseline (785.816 us; speedup 1.0000x reference)
//
#include <hip/hip_runtime.h>
#include <math.h>

// Problem constants
#define NM 20301            // mesh points
#define TT 4096             // time steps
#define NC 64               // t-chunks
#define CH 64               // steps per chunk = TT/NC
#define NBLK 80             // 256-thread n-kernels (density)
#define SBLK 20             // states blocks in n (1024 n per block, 4/thread)
#define NPROW (SBLK * 4)    // 80 per-wave partial rows (speculative)
#define NROWS (NPROW + SBLK)// + 20 block-level correction rows
#define TPH 16              // t-phase width for fused reduce
#define NPH (CH / TPH)      // 4 phases per chunk
#define NFLAGS (NC * SBLK)  // one publish flag per (chunk, n-block)
#define LOG2E_K 1442.69504f // 1000 * log2(e)  (temp = 0.001)
#define WNEAR 26.0f         // saturation cutoff (|z|>=18 natural units)

// Fused soft-relay step (slow path): one rcp instead of two.
__device__ __forceinline__ void relay_step(float ka, float kb, float ku,
                                           float& aa, float& bb) {
    float z1 = fminf(ka - ku, 63.f);
    float z2 = fminf(ku - kb, 63.f);
    float e1 = __builtin_amdgcn_exp2f(z1);
    float e2 = __builtin_amdgcn_exp2f(z2);
    float p1 = 1.f + e1, p2 = 1.f + e2;
    float r  = __builtin_amdgcn_rcpf(p1 * p2);
    aa = (e2 - e1) * r;
    bb = (e1 * e2) * r;
}

__device__ __forceinline__ float wave_reduce_sum(float w) {
    #pragma unroll
    for (int off = 32; off > 0; off >>= 1)
        w += __shfl_down(w, off, 64);
    return w;
}

// ---------------- density MLP: [N,2] -> 16 -> 16 -> 16 -> 1 ----------------
// Also zeroes the publish flags for the fused states kernel (graph-replay /
// ws-re-poison safe: flags reset every launch, stream-ordered before use).
__global__ __launch_bounds__(256) void density_kernel(
    const float* __restrict__ alpha, const float* __restrict__ beta,
    const float* __restrict__ w1, const float* __restrict__ b1,
    const float* __restrict__ w2, const float* __restrict__ b2,
    const float* __restrict__ w3, const float* __restrict__ b3,
    const float* __restrict__ w4, const float* __restrict__ b4,
    float* __restrict__ density_out, float* __restrict__ densum_parts,
    int* __restrict__ flags)
{
    int n = blockIdx.x * 256 + threadIdx.x;
    if (n < NFLAGS) flags[n] = 0;
    bool valid = n < NM;
    int nn = valid ? n : NM - 1;
    float a = alpha[nn], b = beta[nn];

    float h1[16], h2[16], h3[16];
    #pragma unroll
    for (int j = 0; j < 16; j++) {
        float v = fmaf(a, w1[j], fmaf(b, w1[16 + j], b1[j]));
        h1[j] = fmaxf(v, 0.f);
    }
    #pragma unroll
    for (int j = 0; j < 16; j++) {
        float v = b2[j];
        #pragma unroll
        for (int k = 0; k < 16; k++) v = fmaf(h1[k], w2[k * 16 + j], v);
        h2[j] = fmaxf(v, 0.f);
    }
    #pragma unroll
    for (int j = 0; j < 16; j++) {
        float v = b3[j];
        #pragma unroll
        for (int k = 0; k < 16; k++) v = fmaf(h2[k], w3[k * 16 + j], v);
        h3[j] = fmaxf(v, 0.f);
    }
    float v = b4[0];
    #pragma unroll
    for (int k = 0; k < 16; k++) v = fmaf(h3[k], w4[k], v);
    float d = 1.f / (1.f + __expf(-v));

    if (valid) density_out[n] = d;
    float wsum = wave_reduce_sum(valid ? d : 0.f);
    __shared__ float ws_[4];
    if ((threadIdx.x & 63) == 0) ws_[threadIdx.x >> 6] = wsum;
    __syncthreads();
    if (threadIdx.x == 0)
        densum_parts[blockIdx.x] = ws_[0] + ws_[1] + ws_[2] + ws_[3];
}

// ---- fused states: speculative affine pass + decoupled lookback + fixup ---
// Pass 1 tracks s_t = A_t + B_t * s_enter with s_enter unknown; B_t hits
// exact 0 at the first hard saturation (P(no saturation in 64 iid N(0,1)
// steps) < 2e-5), so states[t]=A_t is final for all but a ~5-step prefix.
// Each block publishes its end-of-chunk composite (A,B); lookback composes
// published composites (depth ~1 since B==0) to get s_enter, then the fixup
// rewrites the unresolved prefix and emits an m-correction row.
__global__ __launch_bounds__(256) void states_fused_kernel(
    const float* __restrict__ x, const float* __restrict__ alpha,
    const float* __restrict__ beta, const float* __restrict__ density,
    const float* __restrict__ init_raw,
    float* __restrict__ Acomp, float* __restrict__ Bcomp,
    int* __restrict__ flags,
    float* __restrict__ states, float* __restrict__ partials)
{
    __shared__ float xs[CH];
    __shared__ float tile[4 * 64 * (TPH + 1)];   // 17408 B
    __shared__ float dl[CH];                     // m-correction per t

    int tid = threadIdx.x;
    int c = blockIdx.y, bx = blockIdx.x;
    if (tid < CH) { xs[tid] = x[c * CH + tid] * LOG2E_K; dl[tid] = 0.f; }

    int n0 = bx * 1024 + tid;
    float A[4], B[4], d[4], ka[4], kb[4], s0[4];
    bool v[4];
    #pragma unroll
    for (int q = 0; q < 4; q++) {
        int n = n0 + q * 256;
        v[q] = n < NM;
        int nn = v[q] ? n : NM - 1;
        ka[q] = alpha[nn] * LOG2E_K;
        kb[q] = beta[nn] * LOG2E_K;
        d[q]  = v[q] ? density[n] : 0.f;
        s0[q] = tanhf(init_raw[nn]);   // loaded early: pre-cache-invalidate
        A[q] = 0.f; B[q] = 1.f;
    }
    __syncthreads();   // xs[], dl[]; hot loop below is barrier-free

    int wv = tid >> 6, ln = tid & 63;
    int tl = ln & 15, h = ln >> 4;
    float* wtile = &tile[wv * 64 * (TPH + 1)];
    float* tslot = &wtile[ln * (TPH + 1)];
    float* rp    = states + (size_t)c * CH * NM + n0;   // one vaddr, 4 chains
    size_t prow  = (size_t)(bx * 4 + wv) * TT + c * CH;

    // -------- pass 1: speculative states (affine in unknown s_enter) ------
    for (int p = 0; p < NPH; p++) {
        float xr[TPH];
        #pragma unroll
        for (int j = 0; j < TPH; j++) xr[j] = xs[p * TPH + j];
        #pragma unroll
        for (int j = 0; j < TPH; j++) {
            float u = xr[j];
            #pragma unroll
            for (int q = 0; q < 4; q++) {      // per-q wave-uniform branch
                float d1 = ka[q] - u, d2 = u - kb[q];
                float nr = fminf(fabsf(d1), fabsf(d2));
                if (__any(nr < WNEAR)) {
                    float aa, bb;
                    relay_step(ka[q], kb[q], u, aa, bb);
                    A[q] = fmaf(bb, A[q], aa);
                    B[q] *= bb;
                } else {
                    bool su = d1 < 0.f, sd = d2 < 0.f;
                    A[q] = su ? 1.f : (sd ? -1.f : A[q]);
                    B[q] = (su || sd) ? 0.f : B[q];
                }
                if (v[q]) rp[q * 256] = A[q];  // imm offsets off one vaddr
            }
            rp += NM;
            tslot[j] = fmaf(d[0], A[0], fmaf(d[1], A[1],
                       fmaf(d[2], A[2], d[3] * A[3])));
        }
        // wait own LDS writes only (global stores stay in flight)
        asm volatile("s_waitcnt lgkmcnt(0)" ::: "memory");
        float acc = 0.f;
        #pragma unroll
        for (int k = 0; k < TPH; k++)
            acc += wtile[(h * 16 + k) * (TPH + 1) + tl];  // 2-way banks, free
        acc += __shfl_xor(acc, 16, 64);       // fold 4 n-groups
        acc += __shfl_xor(acc, 32, 64);
        if (ln < TPH) partials[prow + p * TPH + ln] = acc;
        // WAR guard before next phase overwrites the tile
        asm volatile("s_waitcnt lgkmcnt(0)" ::: "memory");
    }

    // -------- publish end-of-chunk composite, then raise the flag ---------
    #pragma unroll
    for (int q = 0; q < 4; q++) {
        if (v[q]) {
            Acomp[(size_t)c * NM + n0 + q * 256] = A[q];
            Bcomp[(size_t)c * NM + n0 + q * 256] = B[q];
        }
    }
    __threadfence();          // device-scope: composites visible cross-XCD
    __syncthreads();
    if (tid == 0)
        __hip_atomic_store(&flags[c * SBLK + bx], 1,
                           __ATOMIC_RELEASE, __HIP_MEMORY_SCOPE_AGENT);

    // -------- lookback: s_enter = P + Q * tanh(init) ----------------------
    float P[4] = {0.f, 0.f, 0.f, 0.f}, Q[4] = {1.f, 1.f, 1.f, 1.f};
    for (int k = c - 1; k >= 0; --k) {
        bool need = (Q[0] != 0.f) | (Q[1] != 0.f) | (Q[2] != 0.f) | (Q[3] != 0.f);
        if (!__any(need)) break;               // typically after depth 1
        float Ak[4], Bk[4];
        int spins = 0; bool have = false;
        while (!have) {
            if (__hip_atomic_load(&flags[k * SBLK + bx],
                                  __ATOMIC_ACQUIRE, __HIP_MEMORY_SCOPE_AGENT)) {
                #pragma unroll
                for (int q = 0; q < 4; q++) {
                    int nn = v[q] ? n0 + q * 256 : NM - 1;
                    Ak[q] = Acomp[(size_t)k * NM + nn];
                    Bk[q] = Bcomp[(size_t)k * NM + nn];
                }
                have = true;
            } else if (++spins > (1 << 16)) {
                // self-help fallback: recompute chunk-k composite locally
                // (deadlock-proof without co-residency assumptions; exact
                // relay everywhere, error <= 1.5e-8 vs published value)
                #pragma unroll
                for (int q = 0; q < 4; q++) { Ak[q] = 0.f; Bk[q] = 1.f; }
                #pragma unroll 1
                for (int j = 0; j < CH; j++) {
                    float u = x[k * CH + j] * LOG2E_K;
                    #pragma unroll
                    for (int q = 0; q < 4; q++) {
                        float aa, bb;
                        relay_step(ka[q], kb[q], u, aa, bb);
                        Ak[q] = fmaf(bb, Ak[q], aa);
                        Bk[q] *= bb;
                    }
                }
                have = true;
            } else {
                __builtin_amdgcn_s_sleep(2);
            }
        }
        #pragma unroll
        for (int q = 0; q < 4; q++) {
            P[q] = fmaf(Q[q], Ak[q], P[q]);
            Q[q] *= Bk[q];
        }
    }
    float ss[4];
    #pragma unroll
    for (int q = 0; q < 4; q++) ss[q] = fmaf(Q[q], s0[q], P[q]);

    // -------- fixup: rewrite unresolved prefix, accumulate corrections ----
    // Replays pass 1's branch decisions bit-exactly (same lanes, same __any)
    // so Af == pass-1 A; steps diverge iff Bf != 0.
    float Af[4] = {0.f, 0.f, 0.f, 0.f}, Bf[4] = {1.f, 1.f, 1.f, 1.f};
    float* rp2 = states + (size_t)c * CH * NM + n0;
    #pragma unroll 1
    for (int j = 0; j < CH; j++) {
        bool live = (Bf[0] != 0.f) | (Bf[1] != 0.f) | (Bf[2] != 0.f) | (Bf[3] != 0.f);
        if (!__any(live)) break;               // typically ~5 steps
        float u = xs[j];
        #pragma unroll
        for (int q = 0; q < 4; q++) {
            float d1 = ka[q] - u, d2 = u - kb[q];
            float nr = fminf(fabsf(d1), fabsf(d2));
            if (__any(nr < WNEAR)) {
                float aa, bb;
                relay_step(ka[q], kb[q], u, aa, bb);
                Af[q] = fmaf(bb, Af[q], aa);
                Bf[q] *= bb;
                ss[q] = fmaf(bb, ss[q], aa);
            } else {
                bool su = d1 < 0.f, sd = d2 < 0.f;
                Af[q] = su ? 1.f : (sd ? -1.f : Af[q]);
                ss[q] = su ? 1.f : (sd ? -1.f : ss[q]);
                Bf[q] = (su || sd) ? 0.f : Bf[q];
            }
            if (Bf[q] != 0.f && v[q]) {        // stored A_t was wrong: fix
                rp2[q * 256] = ss[q];
                atomicAdd(&dl[j], d[q] * (ss[q] - Af[q]));
            }
        }
        rp2 += NM;
    }
    __syncthreads();
    if (tid < CH)   // block-level correction row (disjoint t-slice per c)
        partials[(size_t)(NPROW + bx) * TT + c * CH + tid] = dl[tid];
}

// ---- finalize: fold 80 wave rows + 20 correction rows + 80 densum parts ---
__global__ __launch_bounds__(256) void finalize_kernel(
    const float* __restrict__ x, const float* __restrict__ partials,
    const float* __restrict__ densum_parts,
    const float* __restrict__ msr, const float* __restrict__ mor,
    const float* __restrict__ hsr, float* __restrict__ out)
{
    int t = blockIdx.x * 256 + threadIdx.x;
    if (t >= TT) return;
    float acc = 0.f;
    for (int r = 0; r < NROWS; r++)
        acc += partials[(size_t)r * TT + t];    // coalesced across lanes
    float dsum = 0.f;
    for (int bx = 0; bx < NBLK; bx++)
        dsum += densum_parts[bx];               // uniform -> scalar loads
    float sig_ms = 1.f / (1.f + __expf(-msr[0]));
    float sig_mo = 1.f / (1.f + __expf(-mor[0]));
    float sig_hs = 1.f / (1.f + __expf(-hsr[0]));
    float m_scale  = 10.f * sig_ms;
    float m_offset = fmaf(20.f, sig_mo, -10.f);
    float h_scale  = 10.f * sig_hs;
    float m = acc / dsum;
    out[t] = fmaf(m_scale, m, m_offset) + h_scale * x[t];
}

extern "C" void kernel_launch(void* const* d_in, const int* in_sizes, int n_in,
                              void* d_out, int out_size, void* d_ws, size_t ws_size,
                              hipStream_t stream)
{
    const float* x    = (const float*)d_in[0];   // [4096]
    const float* alpha= (const float*)d_in[1];   // [20301]
    const float* beta = (const float*)d_in[2];   // [20301]
    const float* init = (const float*)d_in[3];   // [20301]
    const float* msr  = (const float*)d_in[4];   // [1]
    const float* mor  = (const float*)d_in[5];   // [1]
    const float* hsr  = (const float*)d_in[6];   // [1]
    const float* w1   = (const float*)d_in[7];
    const float* b1   = (const float*)d_in[8];
    const float* w2   = (const float*)d_in[9];
    const float* b2   = (const float*)d_in[10];
    const float* w3   = (const float*)d_in[11];
    const float* b3   = (const float*)d_in[12];
    const float* w4   = (const float*)d_in[13];
    const float* b4   = (const float*)d_in[14];

    float* out     = (float*)d_out;          // [TT]
    float* density = out + TT;               // [NM]
    float* states  = density + NM;           // [TT*NM]

    // ws: densum_parts[128] | partials[NROWS*TT] | flags[2048 ints]
    //   | Acomp[NC*NM] | Bcomp[NC*NM]            (~11.8 MB total)
    float* densum_parts = (float*)d_ws;
    float* partials     = densum_parts + 128;
    int*   flags        = (int*)(partials + (size_t)NROWS * TT);
    float* Acomp        = (float*)(flags + 2048);
    float* Bcomp        = Acomp + (size_t)NC * NM;

    density_kernel<<<dim3(NBLK), dim3(256), 0, stream>>>(
        alpha, beta, w1, b1, w2, b2, w3, b3, w4, b4,
        density, densum_parts, flags);

    states_fused_kernel<<<dim3(SBLK, NC), dim3(256), 0, stream>>>(
        x, alpha, beta, density, init, Acomp, Bcomp, flags, states, partials);

    finalize_kernel<<<dim3(TT / 256), dim3(256), 0, stream>>>(
        x, partials, densum_parts, msr, mor, hsr, out);
}

// Round 2
// 538.347 us; speedup vs baseline: 1.4597x; 1.4597x over previous
//
#include <hip/hip_runtime.h>
#include <math.h>

// Problem constants
#define NM 20301            // mesh points
#define TT 4096             // time steps
#define NC 64               // t-chunks
#define CH 64               // steps per chunk = TT/NC
#define NBLK 80             // 256-thread n-kernels (density / fixup)
#define SBLK 20             // states blocks in n (1024 n per block, 4/thread)
#define NPROW (SBLK * 4)    // 80 per-wave partial rows (speculative)
#define TPH 16              // t-phase width for fused reduce
#define NPH (CH / TPH)      // 4 phases per chunk
#define LOG2E_K 1442.69504f // 1000 * log2(e)  (temp = 0.001)
#define WNEAR 26.0f         // saturation cutoff (|z|>=18 natural units)

// Fused soft-relay step (slow path): one rcp instead of two.
__device__ __forceinline__ void relay_step(float ka, float kb, float ku,
                                           float& aa, float& bb) {
    float z1 = fminf(ka - ku, 63.f);
    float z2 = fminf(ku - kb, 63.f);
    float e1 = __builtin_amdgcn_exp2f(z1);
    float e2 = __builtin_amdgcn_exp2f(z2);
    float p1 = 1.f + e1, p2 = 1.f + e2;
    float r  = __builtin_amdgcn_rcpf(p1 * p2);
    aa = (e2 - e1) * r;
    bb = (e1 * e2) * r;
}

__device__ __forceinline__ float wave_reduce_sum(float w) {
    #pragma unroll
    for (int off = 32; off > 0; off >>= 1)
        w += __shfl_down(w, off, 64);
    return w;
}

// ---------------- density MLP: [N,2] -> 16 -> 16 -> 16 -> 1 ----------------
// Also zeroes the correction row (ws is re-poisoned between iterations; the
// zeroing is stream-ordered before fixup's atomics -> graph-replay safe).
__global__ __launch_bounds__(256) void density_kernel(
    const float* __restrict__ alpha, const float* __restrict__ beta,
    const float* __restrict__ w1, const float* __restrict__ b1,
    const float* __restrict__ w2, const float* __restrict__ b2,
    const float* __restrict__ w3, const float* __restrict__ b3,
    const float* __restrict__ w4, const float* __restrict__ b4,
    float* __restrict__ density_out, float* __restrict__ densum_parts,
    float* __restrict__ corr)
{
    int n = blockIdx.x * 256 + threadIdx.x;
    if (n < TT) corr[n] = 0.f;
    bool valid = n < NM;
    int nn = valid ? n : NM - 1;
    float a = alpha[nn], b = beta[nn];

    float h1[16], h2[16], h3[16];
    #pragma unroll
    for (int j = 0; j < 16; j++) {
        float v = fmaf(a, w1[j], fmaf(b, w1[16 + j], b1[j]));
        h1[j] = fmaxf(v, 0.f);
    }
    #pragma unroll
    for (int j = 0; j < 16; j++) {
        float v = b2[j];
        #pragma unroll
        for (int k = 0; k < 16; k++) v = fmaf(h1[k], w2[k * 16 + j], v);
        h2[j] = fmaxf(v, 0.f);
    }
    #pragma unroll
    for (int j = 0; j < 16; j++) {
        float v = b3[j];
        #pragma unroll
        for (int k = 0; k < 16; k++) v = fmaf(h2[k], w3[k * 16 + j], v);
        h3[j] = fmaxf(v, 0.f);
    }
    float v = b4[0];
    #pragma unroll
    for (int k = 0; k < 16; k++) v = fmaf(h3[k], w4[k], v);
    float d = 1.f / (1.f + __expf(-v));

    if (valid) density_out[n] = d;
    float wsum = wave_reduce_sum(valid ? d : 0.f);
    __shared__ float ws_[4];
    if ((threadIdx.x & 63) == 0) ws_[threadIdx.x >> 6] = wsum;
    __syncthreads();
    if (threadIdx.x == 0)
        densum_parts[blockIdx.x] = ws_[0] + ws_[1] + ws_[2] + ws_[3];
}

// ---- states pass: speculative affine recurrence, barrier/fence-free -------
// Tracks s_t = A_t + B_t * s_enter with s_enter unknown; B hits exact 0 at
// the first hard saturation (within a few steps for x~N(0,1)), after which
// states[t] = A_t is final. Writes states=A, speculative m-partials, and the
// end-of-chunk composite (A,B) with PLAIN stores -- the consumer (fixup) is
// a separate stream-ordered launch, so no device fence is needed. This is
// the R1 lesson: per-block __threadfence + agent-scope spin flags stalled
// the whole write path (VALUBusy 10%); launch-boundary ordering is free.
__global__ __launch_bounds__(256) void states_spec_kernel(
    const float* __restrict__ x, const float* __restrict__ alpha,
    const float* __restrict__ beta, const float* __restrict__ density,
    float* __restrict__ states, float* __restrict__ partials,
    float* __restrict__ Acomp, float* __restrict__ Bcomp)
{
    __shared__ float xs[CH];
    __shared__ float tile[4 * 64 * (TPH + 1)];   // 17408 B

    int tid = threadIdx.x;
    int c = blockIdx.y;
    if (tid < CH) xs[tid] = x[c * CH + tid] * LOG2E_K;

    int n0 = blockIdx.x * 1024 + tid;
    float A[4], B[4], d[4], ka[4], kb[4];
    bool v[4];
    #pragma unroll
    for (int q = 0; q < 4; q++) {
        int n = n0 + q * 256;
        v[q] = n < NM;
        int nn = v[q] ? n : NM - 1;
        ka[q] = alpha[nn] * LOG2E_K;
        kb[q] = beta[nn] * LOG2E_K;
        d[q]  = v[q] ? density[n] : 0.f;
        A[q] = 0.f; B[q] = 1.f;
    }
    __syncthreads();   // once, for xs[]; hot loop below is barrier-free

    int wv = tid >> 6, ln = tid & 63;
    int tl = ln & 15, h = ln >> 4;
    float* wtile = &tile[wv * 64 * (TPH + 1)];
    float* tslot = &wtile[ln * (TPH + 1)];
    float* rp    = states + (size_t)c * CH * NM + n0;   // one vaddr, 4 chains
    size_t prow  = (size_t)(blockIdx.x * 4 + wv) * TT + c * CH;

    for (int p = 0; p < NPH; p++) {
        float xr[TPH];
        #pragma unroll
        for (int j = 0; j < TPH; j++) xr[j] = xs[p * TPH + j];
        #pragma unroll
        for (int j = 0; j < TPH; j++) {
            float u = xr[j];
            float w1_[4], w2_[4], nr[4];
            #pragma unroll
            for (int q = 0; q < 4; q++) {
                w1_[q] = ka[q] - u;
                w2_[q] = u - kb[q];
                nr[q]  = fminf(fabsf(w1_[q]), fabsf(w2_[q]));
            }
            float nmin = fminf(fminf(nr[0], nr[1]), fminf(nr[2], nr[3]));
            if (__any(nmin < WNEAR)) {           // wave-uniform branch
                #pragma unroll
                for (int q = 0; q < 4; q++) {
                    float aa, bb;
                    relay_step(ka[q], kb[q], u, aa, bb);
                    A[q] = fmaf(bb, A[q], aa);
                    B[q] *= bb;
                }
            } else {
                #pragma unroll
                for (int q = 0; q < 4; q++) {
                    bool su = w1_[q] < 0.f, sd = w2_[q] < 0.f;
                    A[q] = su ? 1.f : (sd ? -1.f : A[q]);
                    B[q] = (su || sd) ? 0.f : B[q];
                }
            }
            #pragma unroll
            for (int q = 0; q < 4; q++)
                if (v[q]) rp[q * 256] = A[q];    // imm offsets off one vaddr
            rp += NM;
            tslot[j] = fmaf(d[0], A[0], fmaf(d[1], A[1],
                       fmaf(d[2], A[2], d[3] * A[3])));
        }
        // wait own LDS writes only (global stores stay in flight)
        asm volatile("s_waitcnt lgkmcnt(0)" ::: "memory");
        float acc = 0.f;
        #pragma unroll
        for (int k = 0; k < TPH; k++)
            acc += wtile[(h * 16 + k) * (TPH + 1) + tl];  // 2-way banks, free
        acc += __shfl_xor(acc, 16, 64);       // fold 4 n-groups
        acc += __shfl_xor(acc, 32, 64);
        if (ln < TPH) partials[prow + p * TPH + ln] = acc;
        // WAR guard before next phase overwrites the tile
        asm volatile("s_waitcnt lgkmcnt(0)" ::: "memory");
    }

    // publish end-of-chunk composite (plain stores; consumed next launch)
    #pragma unroll
    for (int q = 0; q < 4; q++) {
        if (v[q]) {
            Acomp[(size_t)c * NM + n0 + q * 256] = A[q];
            Bcomp[(size_t)c * NM + n0 + q * 256] = B[q];
        }
    }
}

// ---- fixup: sequential composite scan + prefix patch + correction row -----
// One n per thread, 80 blocks. s_enter(c+1) = Acomp(c) + Bcomp(c)*s_enter(c)
// (exact pass-1 trajectory at chunk boundaries). Per chunk, replay with the
// exact relay only until B underflows to 0 (~first saturation, wave-max ~11
// steps), patch states where the stored A was still s_enter-dependent, and
// accumulate the m-correction  corr[t] += sum_n d*Bf*s_enter  via wave
// reduce + one global atomic per wave-step.
__global__ __launch_bounds__(256) void fixup_kernel(
    const float* __restrict__ x, const float* __restrict__ alpha,
    const float* __restrict__ beta, const float* __restrict__ density,
    const float* __restrict__ init_raw,
    const float* __restrict__ Acomp, const float* __restrict__ Bcomp,
    float* __restrict__ states, float* __restrict__ corr)
{
    __shared__ float xs[TT];   // 16 KB: whole scaled input
    int tid = threadIdx.x;
    for (int i = tid; i < TT; i += 256) xs[i] = x[i] * LOG2E_K;

    int n = blockIdx.x * 256 + tid;
    bool valid = n < NM;
    int nn = valid ? n : NM - 1;
    float ka = alpha[nn] * LOG2E_K;
    float kb = beta[nn] * LOG2E_K;
    float d  = valid ? density[n] : 0.f;
    float s  = tanhf(init_raw[nn]);       // s_enter(0)
    __syncthreads();

    int ln = tid & 63;
    // software-prefetch composites one chunk ahead (hides ~500cy load under
    // the replay; only ~1.25 waves/CU resident so TLP won't hide it for us)
    float An = Acomp[nn], Bn = Bcomp[nn];
    for (int c = 0; c < NC; c++) {
        float Ac = An, Bc = Bn;
        if (c + 1 < NC) {
            An = Acomp[(size_t)(c + 1) * NM + nn];
            Bn = Bcomp[(size_t)(c + 1) * NM + nn];
        }
        float Bf = 1.f;
        float ss = s;
        float* rp = states + (size_t)c * CH * NM + n;
        #pragma unroll 1
        for (int j = 0; j < CH; j++) {
            if (!__any(Bf != 0.f)) break;      // all lanes forgot s_enter
            float u = xs[c * CH + j];
            float aa, bb;
            relay_step(ka, kb, u, aa, bb);
            Bf *= bb;
            ss = fmaf(bb, ss, aa);
            if (valid && Bf != 0.f) rp[0] = ss;   // stored A was wrong: fix
            // correction = d * (true_s - speculative_A) = d * Bf * s_enter
            float contrib = wave_reduce_sum(d * Bf * s);
            if (ln == 0 && contrib != 0.f) atomicAdd(&corr[c * CH + j], contrib);
            rp += NM;
        }
        s = fmaf(Bc, s, Ac);                   // advance via exact composite
    }
}

// ---- finalize: fold 80 wave rows + correction row + 80 densum parts -------
__global__ __launch_bounds__(256) void finalize_kernel(
    const float* __restrict__ x, const float* __restrict__ partials,
    const float* __restrict__ corr, const float* __restrict__ densum_parts,
    const float* __restrict__ msr, const float* __restrict__ mor,
    const float* __restrict__ hsr, float* __restrict__ out)
{
    int t = blockIdx.x * 256 + threadIdx.x;
    if (t >= TT) return;
    float acc = corr[t];
    for (int r = 0; r < NPROW; r++)
        acc += partials[(size_t)r * TT + t];    // coalesced across lanes
    float dsum = 0.f;
    for (int bx = 0; bx < NBLK; bx++)
        dsum += densum_parts[bx];               // uniform -> scalar loads
    float sig_ms = 1.f / (1.f + __expf(-msr[0]));
    float sig_mo = 1.f / (1.f + __expf(-mor[0]));
    float sig_hs = 1.f / (1.f + __expf(-hsr[0]));
    float m_scale  = 10.f * sig_ms;
    float m_offset = fmaf(20.f, sig_mo, -10.f);
    float h_scale  = 10.f * sig_hs;
    float m = acc / dsum;
    out[t] = fmaf(m_scale, m, m_offset) + h_scale * x[t];
}

extern "C" void kernel_launch(void* const* d_in, const int* in_sizes, int n_in,
                              void* d_out, int out_size, void* d_ws, size_t ws_size,
                              hipStream_t stream)
{
    const float* x    = (const float*)d_in[0];   // [4096]
    const float* alpha= (const float*)d_in[1];   // [20301]
    const float* beta = (const float*)d_in[2];   // [20301]
    const float* init = (const float*)d_in[3];   // [20301]
    const float* msr  = (const float*)d_in[4];   // [1]
    const float* mor  = (const float*)d_in[5];   // [1]
    const float* hsr  = (const float*)d_in[6];   // [1]
    const float* w1   = (const float*)d_in[7];
    const float* b1   = (const float*)d_in[8];
    const float* w2   = (const float*)d_in[9];
    const float* b2   = (const float*)d_in[10];
    const float* w3   = (const float*)d_in[11];
    const float* b3   = (const float*)d_in[12];
    const float* w4   = (const float*)d_in[13];
    const float* b4   = (const float*)d_in[14];

    float* out     = (float*)d_out;          // [TT]
    float* density = out + TT;               // [NM]
    float* states  = density + NM;           // [TT*NM]

    // ws: densum_parts[128] | corr[TT] | partials[NPROW*TT]
    //   | Acomp[NC*NM] | Bcomp[NC*NM]            (~11.8 MB total)
    float* densum_parts = (float*)d_ws;
    float* corr         = densum_parts + 128;
    float* partials     = corr + TT;
    float* Acomp        = partials + (size_t)NPROW * TT;
    float* Bcomp        = Acomp + (size_t)NC * NM;

    density_kernel<<<dim3(NBLK), dim3(256), 0, stream>>>(
        alpha, beta, w1, b1, w2, b2, w3, b3, w4, b4,
        density, densum_parts, corr);

    states_spec_kernel<<<dim3(SBLK, NC), dim3(256), 0, stream>>>(
        x, alpha, beta, density, states, partials, Acomp, Bcomp);

    fixup_kernel<<<dim3(NBLK), dim3(256), 0, stream>>>(
        x, alpha, beta, density, init, Acomp, Bcomp, states, corr);

    finalize_kernel<<<dim3(TT / 256), dim3(256), 0, stream>>>(
        x, partials, corr, densum_parts, msr, mor, hsr, out);
}

// Round 3
// 448.101 us; speedup vs baseline: 1.7537x; 1.2014x over previous
//
#include <hip/hip_runtime.h>
#include <math.h>

// Problem constants
#define NM 20301            // mesh points
#define TT 4096             // time steps
#define NC 64               // t-chunks
#define CH 64               // steps per chunk = TT/NC
#define NBLK 80             // 256-thread n-kernels (density / senter)
#define SBLK 20             // states blocks in n (1024 n per block, 4/thread)
#define NPROW (SBLK * 4)    // 80 per-wave partial rows (speculative)
#define NROWS (NPROW + 80)  // + 80 patch correction rows (one per bx,wv)
#define TPH 16              // t-phase width for fused reduce
#define NPH (CH / TPH)      // 4 phases per chunk
#define LOG2E_K 1442.69504f // 1000 * log2(e)  (temp = 0.001)
#define WNEAR 26.0f         // saturation cutoff (|z|>=18 natural units)

// Fused soft-relay step (slow path): one rcp instead of two.
__device__ __forceinline__ void relay_step(float ka, float kb, float ku,
                                           float& aa, float& bb) {
    float z1 = fminf(ka - ku, 63.f);
    float z2 = fminf(ku - kb, 63.f);
    float e1 = __builtin_amdgcn_exp2f(z1);
    float e2 = __builtin_amdgcn_exp2f(z2);
    float p1 = 1.f + e1, p2 = 1.f + e2;
    float r  = __builtin_amdgcn_rcpf(p1 * p2);
    aa = (e2 - e1) * r;
    bb = (e1 * e2) * r;
}

__device__ __forceinline__ float wave_reduce_sum(float w) {
    #pragma unroll
    for (int off = 32; off > 0; off >>= 1)
        w += __shfl_down(w, off, 64);
    return w;
}

// ---------------- density MLP: [N,2] -> 16 -> 16 -> 16 -> 1 ----------------
__global__ __launch_bounds__(256) void density_kernel(
    const float* __restrict__ alpha, const float* __restrict__ beta,
    const float* __restrict__ w1, const float* __restrict__ b1,
    const float* __restrict__ w2, const float* __restrict__ b2,
    const float* __restrict__ w3, const float* __restrict__ b3,
    const float* __restrict__ w4, const float* __restrict__ b4,
    float* __restrict__ density_out, float* __restrict__ densum_parts)
{
    int n = blockIdx.x * 256 + threadIdx.x;
    bool valid = n < NM;
    int nn = valid ? n : NM - 1;
    float a = alpha[nn], b = beta[nn];

    float h1[16], h2[16], h3[16];
    #pragma unroll
    for (int j = 0; j < 16; j++) {
        float v = fmaf(a, w1[j], fmaf(b, w1[16 + j], b1[j]));
        h1[j] = fmaxf(v, 0.f);
    }
    #pragma unroll
    for (int j = 0; j < 16; j++) {
        float v = b2[j];
        #pragma unroll
        for (int k = 0; k < 16; k++) v = fmaf(h1[k], w2[k * 16 + j], v);
        h2[j] = fmaxf(v, 0.f);
    }
    #pragma unroll
    for (int j = 0; j < 16; j++) {
        float v = b3[j];
        #pragma unroll
        for (int k = 0; k < 16; k++) v = fmaf(h2[k], w3[k * 16 + j], v);
        h3[j] = fmaxf(v, 0.f);
    }
    float v = b4[0];
    #pragma unroll
    for (int k = 0; k < 16; k++) v = fmaf(h3[k], w4[k], v);
    float d = 1.f / (1.f + __expf(-v));

    if (valid) density_out[n] = d;
    float wsum = wave_reduce_sum(valid ? d : 0.f);
    __shared__ float ws_[4];
    if ((threadIdx.x & 63) == 0) ws_[threadIdx.x >> 6] = wsum;
    __syncthreads();
    if (threadIdx.x == 0)
        densum_parts[blockIdx.x] = ws_[0] + ws_[1] + ws_[2] + ws_[3];
}

// ---- states pass: speculative affine recurrence, barrier/fence-free -------
// Tracks s_t = A_t + B_t * s_enter with s_enter unknown; B hits exact 0 at
// the first hard saturation, after which states[t] = A_t is final. Writes
// states=A, speculative m-partials, and the end-of-chunk composite (A,B)
// with PLAIN stores (consumers are stream-ordered later launches).
// R3: phase loop pinned rolled (#pragma unroll 1) -- the fully unrolled
// 4-phase x 16-step dual-path body was ~44 KB, past the 32 KB I$; rolled
// it is ~11 KB. Hot-loop structure otherwise identical to the proven R0.
__global__ __launch_bounds__(256) void states_spec_kernel(
    const float* __restrict__ x, const float* __restrict__ alpha,
    const float* __restrict__ beta, const float* __restrict__ density,
    float* __restrict__ states, float* __restrict__ partials,
    float* __restrict__ Acomp, float* __restrict__ Bcomp)
{
    __shared__ float xs[CH];
    __shared__ float tile[4 * 64 * (TPH + 1)];   // 17408 B

    int tid = threadIdx.x;
    int c = blockIdx.y;
    if (tid < CH) xs[tid] = x[c * CH + tid] * LOG2E_K;

    int n0 = blockIdx.x * 1024 + tid;
    float A[4], B[4], d[4], ka[4], kb[4];
    bool v[4];
    #pragma unroll
    for (int q = 0; q < 4; q++) {
        int n = n0 + q * 256;
        v[q] = n < NM;
        int nn = v[q] ? n : NM - 1;
        ka[q] = alpha[nn] * LOG2E_K;
        kb[q] = beta[nn] * LOG2E_K;
        d[q]  = v[q] ? density[n] : 0.f;
        A[q] = 0.f; B[q] = 1.f;
    }
    __syncthreads();   // once, for xs[]; hot loop below is barrier-free

    int wv = tid >> 6, ln = tid & 63;
    int tl = ln & 15, h = ln >> 4;
    float* wtile = &tile[wv * 64 * (TPH + 1)];
    float* tslot = &wtile[ln * (TPH + 1)];
    float* rp    = states + (size_t)c * CH * NM + n0;   // one vaddr, 4 chains
    size_t prow  = (size_t)(blockIdx.x * 4 + wv) * TT + c * CH;

    #pragma unroll 1
    for (int p = 0; p < NPH; p++) {
        float xr[TPH];
        #pragma unroll
        for (int j = 0; j < TPH; j++) xr[j] = xs[p * TPH + j];
        #pragma unroll
        for (int j = 0; j < TPH; j++) {
            float u = xr[j];
            float w1_[4], w2_[4], nr[4];
            #pragma unroll
            for (int q = 0; q < 4; q++) {
                w1_[q] = ka[q] - u;
                w2_[q] = u - kb[q];
                nr[q]  = fminf(fabsf(w1_[q]), fabsf(w2_[q]));
            }
            float nmin = fminf(fminf(nr[0], nr[1]), fminf(nr[2], nr[3]));
            if (__any(nmin < WNEAR)) {           // wave-uniform branch
                #pragma unroll
                for (int q = 0; q < 4; q++) {
                    float aa, bb;
                    relay_step(ka[q], kb[q], u, aa, bb);
                    A[q] = fmaf(bb, A[q], aa);
                    B[q] *= bb;
                }
            } else {
                #pragma unroll
                for (int q = 0; q < 4; q++) {
                    bool su = w1_[q] < 0.f, sd = w2_[q] < 0.f;
                    A[q] = su ? 1.f : (sd ? -1.f : A[q]);
                    B[q] = (su || sd) ? 0.f : B[q];
                }
            }
            #pragma unroll
            for (int q = 0; q < 4; q++)
                if (v[q]) rp[q * 256] = A[q];    // imm offsets off one vaddr
            rp += NM;
            tslot[j] = fmaf(d[0], A[0], fmaf(d[1], A[1],
                       fmaf(d[2], A[2], d[3] * A[3])));
        }
        // wait own LDS writes only (global stores stay in flight)
        asm volatile("s_waitcnt lgkmcnt(0)" ::: "memory");
        float acc = 0.f;
        #pragma unroll
        for (int k = 0; k < TPH; k++)
            acc += wtile[(h * 16 + k) * (TPH + 1) + tl];  // 2-way banks, free
        acc += __shfl_xor(acc, 16, 64);       // fold 4 n-groups
        acc += __shfl_xor(acc, 32, 64);
        if (ln < TPH) partials[prow + p * TPH + ln] = acc;
        // WAR guard before next phase overwrites the tile
        asm volatile("s_waitcnt lgkmcnt(0)" ::: "memory");
    }

    // publish end-of-chunk composite (plain stores; consumed next launch)
    #pragma unroll
    for (int q = 0; q < 4; q++) {
        if (v[q]) {
            Acomp[(size_t)c * NM + n0 + q * 256] = A[q];
            Bcomp[(size_t)c * NM + n0 + q * 256] = B[q];
        }
    }
}

// ---- senter scan: s_enter for every chunk, load-latency-free --------------
// Only the 64-step fmaf chain is serial; the 128 composite loads per thread
// are independent. Batch them in register quarters (16 chunks ahead) so the
// chain never waits on memory. Fully unrolled -> all compile-time indices
// (runtime-indexed register arrays would spill to scratch).
__global__ __launch_bounds__(256) void senter_kernel(
    const float* __restrict__ init_raw,
    const float* __restrict__ Acomp, const float* __restrict__ Bcomp,
    float* __restrict__ senter)
{
    int n = blockIdx.x * 256 + threadIdx.x;
    if (n >= NM) return;
    float s = tanhf(init_raw[n]);
    float a0[16], b0[16], a1[16], b1[16];
    #pragma unroll
    for (int k = 0; k < 16; k++) {
        a0[k] = Acomp[(size_t)k * NM + n];
        b0[k] = Bcomp[(size_t)k * NM + n];
    }
    #pragma unroll
    for (int qtr = 0; qtr < 4; qtr++) {
        if (qtr < 3) {          // prefetch next quarter while chaining this
            #pragma unroll
            for (int k = 0; k < 16; k++) {
                if (qtr & 1) {
                    a0[k] = Acomp[(size_t)((qtr + 1) * 16 + k) * NM + n];
                    b0[k] = Bcomp[(size_t)((qtr + 1) * 16 + k) * NM + n];
                } else {
                    a1[k] = Acomp[(size_t)((qtr + 1) * 16 + k) * NM + n];
                    b1[k] = Bcomp[(size_t)((qtr + 1) * 16 + k) * NM + n];
                }
            }
        }
        #pragma unroll
        for (int k = 0; k < 16; k++) {
            senter[(size_t)(qtr * 16 + k) * NM + n] = s;
            if (qtr & 1) s = fmaf(b1[k], s, a1[k]);
            else         s = fmaf(b0[k], s, a0[k]);
        }
    }
}

// ---- patch: parallel prefix fixup, one block per (n-block, chunk) ---------
// 1280 blocks (5/CU) -- no serial chunk loop, no cross-wave atomics (the R2
// fixup's killers: 1.25 waves/CU + 320-way atomic contention on corr[0..]).
// Replays the chunk prefix with the exact relay from s_enter until B
// underflows to exact 0 for the whole wave (~8-12 steps), patches states
// entries that were still s_enter-dependent, and keeps the per-step m
// correction (sum_n d*Bf*s_enter) in a per-lane register: after the
// butterfly reduce, lane j keeps step j's value, so the wave's correction
// row-slice is one coalesced 256 B store (zeros beyond the break point
// included -- required, since ws is re-poisoned between iterations).
__global__ __launch_bounds__(256) void patch_kernel(
    const float* __restrict__ x, const float* __restrict__ alpha,
    const float* __restrict__ beta, const float* __restrict__ density,
    const float* __restrict__ senter,
    float* __restrict__ states, float* __restrict__ partials)
{
    __shared__ float xsl[CH];
    int tid = threadIdx.x;
    int c = blockIdx.y, bx = blockIdx.x;
    if (tid < CH) xsl[tid] = x[c * CH + tid] * LOG2E_K;

    int n0 = bx * 1024 + tid;
    float ka[4], kb[4], d[4], se[4], ss[4], Bf[4];
    bool v[4];
    #pragma unroll
    for (int q = 0; q < 4; q++) {
        int n = n0 + q * 256;
        v[q] = n < NM;
        int nn = v[q] ? n : NM - 1;
        ka[q] = alpha[nn] * LOG2E_K;
        kb[q] = beta[nn] * LOG2E_K;
        d[q]  = v[q] ? density[n] : 0.f;
        se[q] = senter[(size_t)c * NM + nn];
        ss[q] = se[q];
        Bf[q] = 1.f;
    }
    __syncthreads();

    int wv = tid >> 6, ln = tid & 63;
    float myval = 0.f;
    float* rp = states + (size_t)c * CH * NM + n0;
    #pragma unroll 1
    for (int j = 0; j < CH; j++) {
        bool live = (Bf[0] != 0.f) | (Bf[1] != 0.f) |
                    (Bf[2] != 0.f) | (Bf[3] != 0.f);
        if (!__any(live)) break;               // wave-uniform exit
        float u = xsl[j];
        float contrib = 0.f;
        #pragma unroll
        for (int q = 0; q < 4; q++) {
            float aa, bb;
            relay_step(ka[q], kb[q], u, aa, bb);
            Bf[q] *= bb;
            ss[q] = fmaf(bb, ss[q], aa);
            if (Bf[q] != 0.f) {                // stored A_t was wrong: fix
                if (v[q]) rp[q * 256] = ss[q];
                contrib = fmaf(d[q] * Bf[q], se[q], contrib);
            }
        }
        rp += NM;
        #pragma unroll
        for (int off = 1; off < 64; off <<= 1)     // butterfly: all lanes
            contrib += __shfl_xor(contrib, off, 64);
        if (ln == j) myval = contrib;
    }
    partials[(size_t)(NPROW + bx * 4 + wv) * TT + c * CH + ln] = myval;
}

// ---- finalize: fold 80 wave rows + 80 correction rows + 80 densum parts ---
__global__ __launch_bounds__(256) void finalize_kernel(
    const float* __restrict__ x, const float* __restrict__ partials,
    const float* __restrict__ densum_parts,
    const float* __restrict__ msr, const float* __restrict__ mor,
    const float* __restrict__ hsr, float* __restrict__ out)
{
    int t = blockIdx.x * 256 + threadIdx.x;
    if (t >= TT) return;
    float acc = 0.f;
    for (int r = 0; r < NROWS; r++)
        acc += partials[(size_t)r * TT + t];    // coalesced across lanes
    float dsum = 0.f;
    for (int bx = 0; bx < NBLK; bx++)
        dsum += densum_parts[bx];               // uniform -> scalar loads
    float sig_ms = 1.f / (1.f + __expf(-msr[0]));
    float sig_mo = 1.f / (1.f + __expf(-mor[0]));
    float sig_hs = 1.f / (1.f + __expf(-hsr[0]));
    float m_scale  = 10.f * sig_ms;
    float m_offset = fmaf(20.f, sig_mo, -10.f);
    float h_scale  = 10.f * sig_hs;
    float m = acc / dsum;
    out[t] = fmaf(m_scale, m, m_offset) + h_scale * x[t];
}

extern "C" void kernel_launch(void* const* d_in, const int* in_sizes, int n_in,
                              void* d_out, int out_size, void* d_ws, size_t ws_size,
                              hipStream_t stream)
{
    const float* x    = (const float*)d_in[0];   // [4096]
    const float* alpha= (const float*)d_in[1];   // [20301]
    const float* beta = (const float*)d_in[2];   // [20301]
    const float* init = (const float*)d_in[3];   // [20301]
    const float* msr  = (const float*)d_in[4];   // [1]
    const float* mor  = (const float*)d_in[5];   // [1]
    const float* hsr  = (const float*)d_in[6];   // [1]
    const float* w1   = (const float*)d_in[7];
    const float* b1   = (const float*)d_in[8];
    const float* w2   = (const float*)d_in[9];
    const float* b2   = (const float*)d_in[10];
    const float* w3   = (const float*)d_in[11];
    const float* b3   = (const float*)d_in[12];
    const float* w4   = (const float*)d_in[13];
    const float* b4   = (const float*)d_in[14];

    float* out     = (float*)d_out;          // [TT]
    float* density = out + TT;               // [NM]
    float* states  = density + NM;           // [TT*NM]

    // ws: densum_parts[128] | partials[NROWS*TT] | Acomp[NC*NM]
    //   | Bcomp[NC*NM] | senter[NC*NM]          (~18.2 MB total)
    float* densum_parts = (float*)d_ws;
    float* partials     = densum_parts + 128;
    float* Acomp        = partials + (size_t)NROWS * TT;
    float* Bcomp        = Acomp + (size_t)NC * NM;
    float* senter       = Bcomp + (size_t)NC * NM;

    density_kernel<<<dim3(NBLK), dim3(256), 0, stream>>>(
        alpha, beta, w1, b1, w2, b2, w3, b3, w4, b4,
        density, densum_parts);

    states_spec_kernel<<<dim3(SBLK, NC), dim3(256), 0, stream>>>(
        x, alpha, beta, density, states, partials, Acomp, Bcomp);

    senter_kernel<<<dim3(NBLK), dim3(256), 0, stream>>>(
        init, Acomp, Bcomp, senter);

    patch_kernel<<<dim3(SBLK, NC), dim3(256), 0, stream>>>(
        x, alpha, beta, density, senter, states, partials);

    finalize_kernel<<<dim3(TT / 256), dim3(256), 0, stream>>>(
        x, partials, densum_parts, msr, mor, hsr, out);
}